// Round 1
// baseline (380.024 us; speedup 1.0000x reference)
//
#include <hip/hip_runtime.h>
#include <stdint.h>

typedef short bf16x8 __attribute__((ext_vector_type(8)));   // 8 bf16 (4 VGPRs)
typedef float f32x4 __attribute__((ext_vector_type(4)));

#define MFMA16(a,b,c) __builtin_amdgcn_mfma_f32_16x16x32_bf16((a),(b),(c),0,0,0)

__device__ __forceinline__ unsigned short bf16_rne(float f){
  unsigned int u = __builtin_bit_cast(unsigned int, f);
  return (unsigned short)((u + 0x7FFFu + ((u>>16)&1u)) >> 16);
}
__device__ __forceinline__ float bf16_f(unsigned short h){
  unsigned int u = ((unsigned int)h) << 16;
  return __builtin_bit_cast(float, u);
}

// ---------------- workspace layout (bytes) ----------------
// Packed B-fragment streams: [nt][2*KT slots: hi then lo][lane 0..63][j 0..7] bf16
#define SZ_WINIT (48*24*512*2)            // W_init' [768 x 384], KT=12
#define OFF_W0   (SZ_WINIT)
#define SZ_W0    (32*12*512*2)            // W0'    [512 x 192], KT=6
#define OFF_WC   (OFF_W0 + SZ_W0)
#define SZ_WC    (32*8*512*2)             // Wc     [512 x 128], KT=4
#define OFF_BIAS (OFF_WC + SZ_WC)         // bias_init [768] f32

__device__ __forceinline__ void pack_split(unsigned short* __restrict__ base, int KT, int n, int k, float v){
  int nt = n>>4, n16 = n&15, kt = k>>5, kr = k&31;
  int lane = n16 + ((kr>>3)<<4), j = kr&7;
  unsigned short hi = bf16_rne(v);
  unsigned short lo = bf16_rne(v - bf16_f(hi));
  base[((nt*2*KT + kt)*64 + lane)*8 + j] = hi;
  base[((nt*2*KT + KT + kt)*64 + lane)*8 + j] = lo;
}

// Builds composed + split-bf16 packed weights. Re-runs identically every call.
__global__ void decoder_prep(const float* __restrict__ W_ih, const float* __restrict__ W_hh,
                             const float* __restrict__ b_ih, const float* __restrict__ b_hh,
                             const float* __restrict__ W_u0, const float* __restrict__ b_u0,
                             const float* __restrict__ W_h1, const float* __restrict__ b_h1,
                             const float* __restrict__ W_h2, const float* __restrict__ b_h2,
                             unsigned short* __restrict__ wsu, float* __restrict__ bias_out){
  int idx = blockIdx.x*256 + threadIdx.x;
  // ---- W_init' [768 x 384]: rows 0:128 h0 (W_h1), 128:256 c0 (W_h2), 256:768 base (W_ih)
  // cols 0:64 = z-weights, 64:320 = enc-weights, 320:368 = composed x-weights (h rows only)
  if (idx < 768*384) {
    int n = idx/384, k = idx - n*384;
    float v = 0.f;
    if (n < 256) {
      const float* W = (n<128) ? (W_h1 + n*448) : (W_h2 + (n-128)*448);
      if (k < 64) v = W[k];
      else if (k < 320) v = W[192 + k - 64];
      else if (k < 368) { float s = 0.f; int j = k-320;
        for (int c=0;c<128;++c) s += W[64+c]*W_u0[c*48+j];
        v = s; }
    } else {
      int m = n-256;
      if (k < 64) v = W_ih[m*448 + k];
      else if (k < 320) v = W_ih[m*448 + 192 + k - 64];
      // base has no u0/x dependence
    }
    pack_split(wsu, 12, n, k, v);
    return;
  }
  idx -= 768*384;
  // ---- W0' [512 x 192] for t=0: A0=[x(48) | 1 | 0 | h0(64:192)]
  if (idx < 512*192) {
    int n = idx/192, k = idx - n*192;
    float v = 0.f;
    if (k < 48)      { float s=0.f; for (int c=0;c<128;++c) s += W_ih[n*448+64+c]*W_u0[c*48+k]; v = s; }
    else if (k == 48){ float s=0.f; for (int c=0;c<128;++c) s += W_ih[n*448+64+c]*b_u0[c];      v = s; }
    else if (k >= 64)  v = W_hh[n*128 + k - 64];
    pack_split(wsu + OFF_W0/2, 6, n, k, v);
    return;
  }
  idx -= 512*192;
  // ---- Wc [512 x 128] = W_ih[:,64:192] + W_hh   (steps t>=1, since y_t == h_t)
  if (idx < 512*128) {
    int n = idx>>7, k = idx&127;
    float v = W_ih[n*448 + 64 + k] + W_hh[n*128 + k];
    pack_split(wsu + OFF_WC/2, 4, n, k, v);
    return;
  }
  idx -= 512*128;
  // ---- bias_init [768] = [b_h1 + Wh1_u@b_u0 ; b_h2 + Wh2_u@b_u0 ; b_ih+b_hh]
  if (idx < 768) {
    float v;
    if (idx < 256) {
      const float* W  = (idx<128) ? (W_h1 + idx*448) : (W_h2 + (idx-128)*448);
      float s = (idx<128) ? b_h1[idx] : b_h2[idx-128];
      for (int c=0;c<128;++c) s += W[64+c]*b_u0[c];
      v = s;
    } else v = b_ih[idx-256] + b_hh[idx-256];
    bias_out[idx] = v;
  }
}

// ---------------- LDS layout (bytes), total 76800 ----------------
// [0      ,12800) a0_hi [32][200] bf16     (A0 = [x|1|0|h0], K=192 padded)
// [12800  ,25600) a0_lo
// [25600  ,50688) xi_hi [32][392] bf16     (setup A, K=384 padded)   -- dead after setup
// [50688  ,75776) xi_lo                                             -- dead after setup
// overlay after setup:
// [25600  ,43008) h_hi  [2][32][136] bf16  (double-buffered h)
// [43008  ,60416) h_lo  [2][32][136]
// [60416  ,76800) c0    [32][128] f32      (one-shot c0 exchange)

__global__ __launch_bounds__(512, 2)
void decoder_main(const float* __restrict__ x, const float* __restrict__ enc, const float* __restrict__ z,
                  const unsigned short* __restrict__ wsu, const float* __restrict__ bias_init,
                  const int* __restrict__ hz, float* __restrict__ out){
  extern __shared__ char smem[];
  unsigned short* a0_hi = (unsigned short*)(smem);
  unsigned short* a0_lo = (unsigned short*)(smem + 12800);
  unsigned short* xi_hi = (unsigned short*)(smem + 25600);
  unsigned short* xi_lo = (unsigned short*)(smem + 50688);
  unsigned short* hbh   = (unsigned short*)(smem + 25600);
  unsigned short* hbl   = (unsigned short*)(smem + 43008);
  float*          c0l   = (float*)(smem + 60416);

  const int tid = threadIdx.x;
  const int w = tid>>6, lane = tid&63, n16 = lane&15, p = lane>>4;
  const int R0 = blockIdx.x*32;
  const int T = hz[0];

  // ---- phase 1: stage split inputs ----
  for (int i = tid; i < 32*384; i += 512) {
    int r = i/384, c = i - r*384;
    float v;
    if (c < 64)       v = z[(R0+r)*64 + c];
    else if (c < 320) v = enc[(R0+r)*256 + c - 64];
    else if (c < 368) v = x[(R0+r)*48 + c - 320];
    else              v = 0.f;
    unsigned short hi = bf16_rne(v);
    xi_hi[r*392 + c] = hi;
    xi_lo[r*392 + c] = bf16_rne(v - bf16_f(hi));
  }
  for (int i = tid; i < 32*64; i += 512) {
    int r = i>>6, c = i&63;
    float v = (c<48) ? x[(R0+r)*48 + c] : (c==48 ? 1.f : 0.f);
    unsigned short hi = bf16_rne(v);
    a0_hi[r*200 + c] = hi;
    a0_lo[r*200 + c] = bf16_rne(v - bf16_f(hi));
  }
  __syncthreads();

  // ---- phase 2: setup GEMM  [h0|c0|base](32x768) = xi(32x384) @ W_init'^T + bias ----
  // wave w owns n-tiles {2w, 2w+1} (h0/c0) and {16+8q+w : q=0..3} (base)
  const bf16x8* WIp = (const bf16x8*)wsu;
  f32x4 accs[6][2];
  #pragma unroll
  for (int i=0;i<6;++i){
    int nt = (i<2) ? (2*w+i) : (16 + 8*(i-2) + w);
    float b = bias_init[nt*16 + n16];
    accs[i][0] = (f32x4){b,b,b,b};
    accs[i][1] = accs[i][0];
  }
  for (int kt=0; kt<12; ++kt) {
    bf16x8 ah0 = *(const bf16x8*)(xi_hi +      n16 *392 + kt*32 + p*8);
    bf16x8 ah1 = *(const bf16x8*)(xi_hi + (16+n16)*392 + kt*32 + p*8);
    bf16x8 al0 = *(const bf16x8*)(xi_lo +      n16 *392 + kt*32 + p*8);
    bf16x8 al1 = *(const bf16x8*)(xi_lo + (16+n16)*392 + kt*32 + p*8);
    #pragma unroll
    for (int i=0;i<6;++i){
      int nt = (i<2) ? (2*w+i) : (16 + 8*(i-2) + w);
      const bf16x8* fp = WIp + ((unsigned)(nt*24 + kt))*64 + lane;
      bf16x8 bh = fp[0];
      bf16x8 bl = fp[12*64];
      accs[i][0] = MFMA16(ah0, bh, accs[i][0]);
      accs[i][1] = MFMA16(ah1, bh, accs[i][1]);
      accs[i][0] = MFMA16(al0, bh, accs[i][0]);
      accs[i][1] = MFMA16(al1, bh, accs[i][1]);
      accs[i][0] = MFMA16(ah0, bl, accs[i][0]);
      accs[i][1] = MFMA16(ah1, bl, accs[i][1]);
    }
  }
  __syncthreads();   // xi now dead; safe to publish h0/c0 into overlay regions

  // ---- phase 3: distribute h0 -> a0 LDS, c0 -> LDS; base stays in regs ----
  #pragma unroll
  for (int i=0;i<2;++i){
    int ntg = 2*w + i;
    #pragma unroll
    for (int mt=0;mt<2;++mt){
      #pragma unroll
      for (int e=0;e<4;++e){
        int row = mt*16 + p*4 + e;           // C/D layout: row=(lane>>4)*4+reg
        float v = accs[i][mt][e];
        if (ntg < 8) {                        // h0 tile
          int col = 64 + ntg*16 + n16;
          unsigned short hi = bf16_rne(v);
          a0_hi[row*200 + col] = hi;
          a0_lo[row*200 + col] = bf16_rne(v - bf16_f(hi));
        } else {                              // c0 tile
          c0l[row*128 + (ntg-8)*16 + n16] = v;
        }
      }
    }
  }
  __syncthreads();

  f32x4 creg[2];
  #pragma unroll
  for (int mt=0;mt<2;++mt)
    #pragma unroll
    for (int e=0;e<4;++e)
      creg[mt][e] = c0l[(mt*16 + p*4 + e)*128 + w*16 + n16];

  f32x4 base_r[2][4];
  #pragma unroll
  for (int q=0;q<4;++q)
    #pragma unroll
    for (int mt=0;mt<2;++mt)
      base_r[mt][q] = accs[2+q][mt];

  // ---- persistent step weights Wc (hi+lo) in registers: 32 frags = 128 VGPR ----
  const bf16x8* WCp = (const bf16x8*)(wsu + OFF_WC/2);
  bf16x8 wchi[4][4], wclo[4][4];
  #pragma unroll
  for (int q=0;q<4;++q){
    int nt = 8*q + w;
    #pragma unroll
    for (int kt=0;kt<4;++kt){
      wchi[q][kt] = WCp[((unsigned)(nt*8 + kt))*64 + lane];
      wclo[q][kt] = WCp[((unsigned)(nt*8 + 4 + kt))*64 + lane];
    }
  }

  unsigned rt[2][4];
  #pragma unroll
  for (int mt=0;mt<2;++mt)
    #pragma unroll
    for (int e=0;e<4;++e)
      rt[mt][e] = (unsigned)(R0 + mt*16 + p*4 + e)*(unsigned)(T*128) + (unsigned)(w*16 + n16);

  f32x4 acc[2][4];
  const float K1 = 1.44269504088896340736f;   // log2(e)
  const float K2 = 2.88539008177792681472f;   // 2*log2(e)

  // register-local LSTM cell update; wave owns i/f/g/o at identical (row,col) slots
  auto lstm_tail = [&](int t, int wb){
    #pragma unroll
    for (int mt=0;mt<2;++mt){
      #pragma unroll
      for (int e=0;e<4;++e){
        float iv = acc[mt][0][e], fv = acc[mt][1][e], gv = acc[mt][2][e], ov = acc[mt][3][e];
        float c = creg[mt][e];
        float ef = __builtin_amdgcn_exp2f(-K1*fv);
        float sf = __builtin_amdgcn_rcpf(1.f + ef);                  // sigmoid(f)
        float ei = __builtin_amdgcn_exp2f(-K1*iv);
        float eg = __builtin_amdgcn_exp2f(-K2*gv);
        float d  = __builtin_amdgcn_rcpf((1.f+ei)*(1.f+eg));
        c = sf*c + (1.f-eg)*d;                                       // + sig(i)*tanh(g)
        float eo = __builtin_amdgcn_exp2f(-K1*ov);
        float ec = __builtin_amdgcn_exp2f(-K2*c);
        float h  = (1.f-ec)*__builtin_amdgcn_rcpf((1.f+eo)*(1.f+ec)); // sig(o)*tanh(c)
        creg[mt][e] = c;
        out[rt[mt][e] + (unsigned)(t*128)] = h;
        int row = mt*16 + p*4 + e;
        unsigned short hh = bf16_rne(h);
        hbh[wb*4352 + row*136 + w*16 + n16] = hh;
        hbl[wb*4352 + row*136 + w*16 + n16] = bf16_rne(h - bf16_f(hh));
      }
    }
  };

  // ---- t = 0: gates = base + [x|1|h0] @ W0'^T ----
  {
    const bf16x8* W0p = (const bf16x8*)(wsu + OFF_W0/2);
    #pragma unroll
    for (int kt=0;kt<6;++kt){
      bf16x8 ah0 = *(const bf16x8*)(a0_hi +      n16 *200 + kt*32 + p*8);
      bf16x8 ah1 = *(const bf16x8*)(a0_hi + (16+n16)*200 + kt*32 + p*8);
      bf16x8 al0 = *(const bf16x8*)(a0_lo +      n16 *200 + kt*32 + p*8);
      bf16x8 al1 = *(const bf16x8*)(a0_lo + (16+n16)*200 + kt*32 + p*8);
      #pragma unroll
      for (int q=0;q<4;++q){
        const bf16x8* fp = W0p + ((unsigned)((8*q+w)*12 + kt))*64 + lane;
        bf16x8 bh = fp[0];
        bf16x8 bl = fp[6*64];
        #pragma unroll
        for (int mt=0;mt<2;++mt){
          bf16x8 ah = mt ? ah1 : ah0;
          bf16x8 al = mt ? al1 : al0;
          f32x4 ci = (kt==0) ? base_r[mt][q] : acc[mt][q];
          ci = MFMA16(ah, bh, ci);
          ci = MFMA16(al, bh, ci);
          ci = MFMA16(ah, bl, ci);
          acc[mt][q] = ci;
        }
      }
    }
    lstm_tail(0, 0);
  }
  __syncthreads();

  // ---- t = 1..T-1: gates = base + h @ Wc^T (register weights, LDS h double-buffer) ----
  for (int t=1; t<T; ++t){
    const int rb = (t-1)&1, wb = t&1;
    const unsigned short* hr = hbh + rb*4352;
    const unsigned short* lr = hbl + rb*4352;
    #pragma unroll
    for (int kt=0;kt<4;++kt){
      bf16x8 ah0 = *(const bf16x8*)(hr +      n16 *136 + kt*32 + p*8);
      bf16x8 ah1 = *(const bf16x8*)(hr + (16+n16)*136 + kt*32 + p*8);
      bf16x8 al0 = *(const bf16x8*)(lr +      n16 *136 + kt*32 + p*8);
      bf16x8 al1 = *(const bf16x8*)(lr + (16+n16)*136 + kt*32 + p*8);
      #pragma unroll
      for (int q=0;q<4;++q){
        #pragma unroll
        for (int mt=0;mt<2;++mt){
          bf16x8 ah = mt ? ah1 : ah0;
          bf16x8 al = mt ? al1 : al0;
          f32x4 ci = (kt==0) ? base_r[mt][q] : acc[mt][q];
          ci = MFMA16(ah, wchi[q][kt], ci);
          ci = MFMA16(al, wchi[q][kt], ci);
          ci = MFMA16(ah, wclo[q][kt], ci);
          acc[mt][q] = ci;
        }
      }
    }
    lstm_tail(t, wb);
    __syncthreads();
  }
}

extern "C" void kernel_launch(void* const* d_in, const int* in_sizes, int n_in,
                              void* d_out, int out_size, void* d_ws, size_t ws_size,
                              hipStream_t stream) {
    (void)in_sizes; (void)n_in; (void)out_size; (void)ws_size;
    const float* x    = (const float*)d_in[0];
    const float* enc  = (const float*)d_in[1];
    const float* z    = (const float*)d_in[2];
    const float* W_ih = (const float*)d_in[3];
    const float* W_hh = (const float*)d_in[4];
    const float* b_ih = (const float*)d_in[5];
    const float* b_hh = (const float*)d_in[6];
    const float* W_u0 = (const float*)d_in[7];
    const float* b_u0 = (const float*)d_in[8];
    const float* W_h1 = (const float*)d_in[9];
    const float* b_h1 = (const float*)d_in[10];
    const float* W_h2 = (const float*)d_in[11];
    const float* b_h2 = (const float*)d_in[12];
    const int*   hz   = (const int*)d_in[13];
    float* out = (float*)d_out;
    unsigned short* wsu = (unsigned short*)d_ws;
    float* bias = (float*)((char*)d_ws + OFF_BIAS);

    // allow 76800 B dynamic LDS (gfx950 supports up to 160 KiB/WG); idempotent, capture-safe
    (void)hipFuncSetAttribute((const void*)decoder_main,
                              hipFuncAttributeMaxDynamicSharedMemorySize, 76800);

    decoder_prep<<<dim3(1795), dim3(256), 0, stream>>>(W_ih, W_hh, b_ih, b_hh, W_u0, b_u0,
                                                       W_h1, b_h1, W_h2, b_h2, wsu, bias);
    decoder_main<<<dim3(256), dim3(512), 76800, stream>>>(x, enc, z, wsu, bias, hz, out);
}

// Round 2
// 374.870 us; speedup vs baseline: 1.0137x; 1.0137x over previous
//
#include <hip/hip_runtime.h>
#include <stdint.h>

typedef short bf16x8 __attribute__((ext_vector_type(8)));     // 8 bf16 (4 VGPRs)
typedef float f32x4 __attribute__((ext_vector_type(4)));
typedef unsigned short u16x4 __attribute__((ext_vector_type(4)));  // 8B LDS store

#define MFMA16(a,b,c) __builtin_amdgcn_mfma_f32_16x16x32_bf16((a),(b),(c),0,0,0)

__device__ __forceinline__ unsigned short bf16_rne(float f){
  unsigned int u = __builtin_bit_cast(unsigned int, f);
  return (unsigned short)((u + 0x7FFFu + ((u>>16)&1u)) >> 16);
}
__device__ __forceinline__ float bf16_f(unsigned short h){
  unsigned int u = ((unsigned int)h) << 16;
  return __builtin_bit_cast(float, u);
}

// ---------------- workspace layout (bytes) ----------------
// Packed A-fragment streams: [nt][2*KT slots: hi then lo][lane 0..63][j 0..7] bf16
#define SZ_WINIT (48*24*512*2)            // W_init' [768 x 384], KT=12
#define OFF_W0   (SZ_WINIT)
#define SZ_W0    (32*12*512*2)            // W0'    [512 x 192], KT=6
#define OFF_WC   (OFF_W0 + SZ_W0)
#define SZ_WC    (32*8*512*2)             // Wc     [512 x 128], KT=4
#define OFF_BIAS (OFF_WC + SZ_WC)         // bias_init [768] f32
#define OFF_XQ   (OFF_BIAS + 4096)        // Xq [512 x 49] f32 (W_ih_y @ [W_u0 | b_u0])
#define OFF_XH   (OFF_XQ + 512*49*4)      // Xh [256 x 49] f32 (W_h1/2_y @ [W_u0 | b_u0])

// ---------- P1: compose the u0-foldings (tiny GEMMs, LDS-tiled) ----------
__global__ __launch_bounds__(256)
void decoder_compose(const float* __restrict__ W_ih, const float* __restrict__ W_u0,
                     const float* __restrict__ b_u0, const float* __restrict__ W_h1,
                     const float* __restrict__ W_h2, float* __restrict__ ws){
  __shared__ float wu[128][49];
  __shared__ float wrow[16][128];
  float* Xq = (float*)((char*)ws + OFF_XQ);
  float* Xh = (float*)((char*)ws + OFF_XH);
  const int b = blockIdx.x, tid = threadIdx.x;
  for (int i = tid; i < 128*49; i += 256){
    int c = i/49, j = i - c*49;
    wu[c][j] = (j < 48) ? W_u0[c*48 + j] : b_u0[c];
  }
  for (int i = tid; i < 16*128; i += 256){
    int r = i>>7, c = i&127;
    const float* src;
    if (b < 32) src = W_ih + (b*16 + r)*448 + 64;
    else { int mm = (b-32)*16 + r; src = (mm<128) ? (W_h1 + mm*448 + 64) : (W_h2 + (mm-128)*448 + 64); }
    wrow[r][c] = src[c];
  }
  __syncthreads();
  for (int o = tid; o < 16*49; o += 256){
    int r = o/49, j = o - r*49;
    float s = 0.f;
    #pragma unroll 8
    for (int c = 0; c < 128; ++c) s += wrow[r][c]*wu[c][j];
    if (b < 32) Xq[(b*16+r)*49 + j] = s;
    else        Xh[((b-32)*16+r)*49 + j] = s;
  }
}

// ---------- P2: pack split-bf16 fragment streams (1 thread = 1 fragment) ----------
__global__ __launch_bounds__(256)
void decoder_pack(const float* __restrict__ W_ih, const float* __restrict__ W_hh,
                  const float* __restrict__ b_ih, const float* __restrict__ b_hh,
                  const float* __restrict__ W_h1, const float* __restrict__ W_h2,
                  const float* __restrict__ b_h1, const float* __restrict__ b_h2,
                  unsigned short* __restrict__ wsu, float* __restrict__ ws){
  const float* Xq = (const float*)((const char*)ws + OFF_XQ);
  const float* Xh = (const float*)((const char*)ws + OFF_XH);
  float* bias = (float*)((char*)ws + OFF_BIAS);
  const int gid = blockIdx.x*256 + threadIdx.x;
  const int slot = gid >> 6, lane = gid & 63;
  const int n16 = lane & 15, p = lane >> 4;

  float v[8];
  unsigned short* dh; unsigned short* dl;
  if (slot < 576) {                        // W_init' [768 x 384], KT=12
    int nt = slot/12, kt = slot - nt*12;
    int n = nt*16 + n16;
    #pragma unroll
    for (int j=0;j<8;++j){
      int k = kt*32 + p*8 + j;
      float xv = 0.f;
      if (n < 256) {
        const float* W = (n<128) ? (W_h1 + n*448) : (W_h2 + (n-128)*448);
        if (k < 64) xv = W[k];
        else if (k < 320) xv = W[192 + k - 64];
        else if (k < 368) xv = Xh[n*49 + (k-320)];
      } else {
        int m = n - 256;
        if (k < 64) xv = W_ih[m*448 + k];
        else if (k < 320) xv = W_ih[m*448 + 192 + k - 64];
      }
      v[j] = xv;
    }
    dh = wsu + ((nt*24 + kt)*64 + lane)*8;
    dl = wsu + ((nt*24 + 12 + kt)*64 + lane)*8;
  } else if (slot < 768) {                 // W0' [512 x 192], KT=6
    int s2 = slot - 576;
    int nt = s2/6, kt = s2 - nt*6;
    int n = nt*16 + n16;
    #pragma unroll
    for (int j=0;j<8;++j){
      int k = kt*32 + p*8 + j;
      float xv = 0.f;
      if (k < 49)      xv = Xq[n*49 + k];
      else if (k >= 64) xv = W_hh[n*128 + k - 64];
      v[j] = xv;
    }
    unsigned short* b = wsu + OFF_W0/2;
    dh = b + ((nt*12 + kt)*64 + lane)*8;
    dl = b + ((nt*12 + 6 + kt)*64 + lane)*8;
  } else if (slot < 896) {                 // Wc [512 x 128], KT=4
    int s3 = slot - 768;
    int nt = s3>>2, kt = s3&3;
    int n = nt*16 + n16;
    #pragma unroll
    for (int j=0;j<8;++j){
      int k = kt*32 + p*8 + j;
      v[j] = W_ih[n*448 + 64 + k] + W_hh[n*128 + k];
    }
    unsigned short* b = wsu + OFF_WC/2;
    dh = b + ((nt*8 + kt)*64 + lane)*8;
    dl = b + ((nt*8 + 4 + kt)*64 + lane)*8;
  } else {                                 // bias_init [768]
    int i = gid - 896*64;
    if (i < 768) {
      float bv;
      if (i < 128)      bv = b_h1[i] + Xh[i*49 + 48];
      else if (i < 256) bv = b_h2[i-128] + Xh[i*49 + 48];
      else              bv = b_ih[i-256] + b_hh[i-256];
      bias[i] = bv;
    }
    return;
  }
  bf16x8 vh, vl;
  #pragma unroll
  for (int j=0;j<8;++j){
    unsigned short h = bf16_rne(v[j]);
    vh[j] = (short)h;
    vl[j] = (short)bf16_rne(v[j] - bf16_f(h));
  }
  *(bf16x8*)dh = vh;
  *(bf16x8*)dl = vl;
}

// ---------------- LDS layout (bytes), total 73728 ----------------
// [0     ,12288) a0_hi [32 rows][192 u] bf16, pitch 384B, XOR16 swizzle
// [12288 ,24576) a0_lo
// [24576 ,49152) xi_hi [32][384], pitch 768B, XOR16     -- dead after setup
// [49152 ,73728) xi_lo
// overlay after setup:
// [24576 ,57344) h planes: [buf2][hi/lo][32][128] bf16, pitch 256B, XOR16 (4 x 8192B)
#define LDS_A0H 0
#define LDS_A0L 12288
#define LDS_XIH 24576
#define LDS_XIL 49152
#define LDS_H   24576
#define LDS_TOTAL 73728

__global__ __launch_bounds__(512, 2)
void decoder_main(const float* __restrict__ x, const float* __restrict__ enc, const float* __restrict__ z,
                  const unsigned short* __restrict__ wsu, const float* __restrict__ bias,
                  const int* __restrict__ hz, float* __restrict__ out){
  extern __shared__ char smem[];
  const int tid = threadIdx.x;
  const int w = tid>>6, lane = tid&63, n16 = lane&15, p = lane>>4;
  const int p16 = p*16;
  const int R0 = blockIdx.x*32;
  const int T = hz[0];

  // ---- phase 1: stage split inputs (XOR16-swizzled rows) ----
  for (int i = tid; i < 32*384; i += 512){
    int r = i/384, c = i - r*384;
    float v;
    if (c < 64)       v = z[(R0+r)*64 + c];
    else if (c < 320) v = enc[(R0+r)*256 + c - 64];
    else if (c < 368) v = x[(R0+r)*48 + c - 320];
    else              v = 0.f;
    unsigned short h = bf16_rne(v);
    int off = r*768 + ((2*c) ^ ((r&7)<<4));
    *(unsigned short*)(smem + LDS_XIH + off) = h;
    *(unsigned short*)(smem + LDS_XIL + off) = bf16_rne(v - bf16_f(h));
  }
  for (int i = tid; i < 32*64; i += 512){
    int r = i>>6, c = i&63;
    float v = (c < 48) ? x[(R0+r)*48 + c] : (c == 48 ? 1.f : 0.f);
    unsigned short h = bf16_rne(v);
    int off = r*384 + ((2*c) ^ ((r&7)<<4));
    *(unsigned short*)(smem + LDS_A0H + off) = h;
    *(unsigned short*)(smem + LDS_A0L + off) = bf16_rne(v - bf16_f(h));
  }
  __syncthreads();

  const int row0 = n16, row1 = 16 + n16;
  const int s0 = (row0&7)<<4, s1 = (row1&7)<<4;

  // ---- phase 2: setup GEMM (swapped: D[m=768 out][n=32 batch] = W_init'(A) x xi^T(B)) ----
  // wave w tiles: i=0 -> w (h0), i=1 -> 8+w (c0), i=2+q -> 16+8q+w (base)
  f32x4 accs[6][2];
  #pragma unroll
  for (int i=0;i<6;++i){
    int nt = (i==0) ? w : (i==1) ? (8+w) : (16 + 8*(i-2) + w);
    f32x4 bv = *(const f32x4*)(bias + nt*16 + p*4);
    accs[i][0] = bv; accs[i][1] = bv;
  }
  #pragma unroll
  for (int kt=0; kt<12; ++kt){
    bf16x8 bh0 = *(const bf16x8*)(smem + LDS_XIH + row0*768 + ((kt*64 + p16) ^ s0));
    bf16x8 bh1 = *(const bf16x8*)(smem + LDS_XIH + row1*768 + ((kt*64 + p16) ^ s1));
    bf16x8 bl0 = *(const bf16x8*)(smem + LDS_XIL + row0*768 + ((kt*64 + p16) ^ s0));
    bf16x8 bl1 = *(const bf16x8*)(smem + LDS_XIL + row1*768 + ((kt*64 + p16) ^ s1));
    bf16x8 wa[6], wl[6];
    #pragma unroll
    for (int i=0;i<6;++i){
      if (kt >= 10 && i >= 2) continue;      // base x-columns are zero
      int nt = (i==0) ? w : (i==1) ? (8+w) : (16 + 8*(i-2) + w);
      wa[i] = *(const bf16x8*)(wsu + ((nt*24 + kt)*64 + lane)*8);
      wl[i] = *(const bf16x8*)(wsu + ((nt*24 + 12 + kt)*64 + lane)*8);
    }
    #pragma unroll
    for (int i=0;i<6;++i){ if (kt >= 10 && i >= 2) continue;
      accs[i][0] = MFMA16(wa[i], bh0, accs[i][0]);
      accs[i][1] = MFMA16(wa[i], bh1, accs[i][1]); }
    #pragma unroll
    for (int i=0;i<6;++i){ if (kt >= 10 && i >= 2) continue;
      accs[i][0] = MFMA16(wa[i], bl0, accs[i][0]);
      accs[i][1] = MFMA16(wa[i], bl1, accs[i][1]); }
    #pragma unroll
    for (int i=0;i<6;++i){ if (kt >= 10 && i >= 2) continue;
      accs[i][0] = MFMA16(wl[i], bh0, accs[i][0]);
      accs[i][1] = MFMA16(wl[i], bh1, accs[i][1]); }
  }
  __syncthreads();   // xi dead; overlay region becomes h buffers

  // ---- phase 3: publish h0 into a0 (cols 64+u); c0/base stay in regs ----
  #pragma unroll
  for (int bt=0; bt<2; ++bt){
    int row = bt*16 + n16, s = (row&7)<<4;
    u16x4 vh, vl;
    #pragma unroll
    for (int e=0;e<4;++e){
      float hv = accs[0][bt][e];
      unsigned short h = bf16_rne(hv);
      vh[e] = h; vl[e] = bf16_rne(hv - bf16_f(h));
    }
    int off = row*384 + ((128 + 32*w + 8*p) ^ s);
    *(u16x4*)(smem + LDS_A0H + off) = vh;
    *(u16x4*)(smem + LDS_A0L + off) = vl;
  }
  f32x4 creg[2] = { accs[1][0], accs[1][1] };
  f32x4 base_r[2][4];
  #pragma unroll
  for (int q=0;q<4;++q){ base_r[0][q] = accs[2+q][0]; base_r[1][q] = accs[2+q][1]; }
  __syncthreads();

  float* outp0 = out + (size_t)(R0 + n16)      * (size_t)(T*128) + (16*w + 4*p);
  float* outp1 = out + (size_t)(R0 + 16 + n16) * (size_t)(T*128) + (16*w + 4*p);

  f32x4 acc[2][4];
  f32x4 hcur0, hcur1;
  const float K1 = 1.44269504088896340736f;   // log2(e)
  const float K2 = 2.88539008177792681472f;   // 2*log2(e)

  // register-local LSTM cell update; thread owns i/f/g/o for units 16w+4p+e, batch bt*16+n16
  auto lstm_tail = [&](int wb){
    #pragma unroll
    for (int bt=0; bt<2; ++bt){
      f32x4 hh;
      #pragma unroll
      for (int e=0;e<4;++e){
        float iv = acc[bt][0][e], fv = acc[bt][1][e], gv = acc[bt][2][e], ov = acc[bt][3][e];
        float c = creg[bt][e];
        float ef = __builtin_amdgcn_exp2f(-K1*fv);
        float sf = __builtin_amdgcn_rcpf(1.f + ef);                    // sigmoid(f)
        float ei = __builtin_amdgcn_exp2f(-K1*iv);
        float eg = __builtin_amdgcn_exp2f(-K2*gv);
        float d  = __builtin_amdgcn_rcpf((1.f+ei)*(1.f+eg));
        c = sf*c + (1.f-eg)*d;                                         // + sig(i)*tanh(g)
        float eo = __builtin_amdgcn_exp2f(-K1*ov);
        float ec = __builtin_amdgcn_exp2f(-K2*c);
        float h  = (1.f-ec)*__builtin_amdgcn_rcpf((1.f+eo)*(1.f+ec));  // sig(o)*tanh(c)
        creg[bt][e] = c; hh[e] = h;
      }
      if (bt == 0) hcur0 = hh; else hcur1 = hh;
      int row = bt*16 + n16, s = (row&7)<<4;
      u16x4 ph, pl;
      #pragma unroll
      for (int e=0;e<4;++e){
        unsigned short h = bf16_rne(hh[e]);
        ph[e] = h; pl[e] = bf16_rne(hh[e] - bf16_f(h));
      }
      int off = row*256 + ((32*w + 8*p) ^ s);
      *(u16x4*)(smem + LDS_H + (wb*2+0)*8192 + off) = ph;
      *(u16x4*)(smem + LDS_H + (wb*2+1)*8192 + off) = pl;
    }
  };

  // ---- t = 0: gates = base + W0'(A) x [x|1|h0]^T(B) ----
  {
    const unsigned short* W0p = wsu + OFF_W0/2;
    #pragma unroll
    for (int kt=0; kt<6; ++kt){
      bf16x8 bh0 = *(const bf16x8*)(smem + LDS_A0H + row0*384 + ((kt*64 + p16) ^ s0));
      bf16x8 bh1 = *(const bf16x8*)(smem + LDS_A0H + row1*384 + ((kt*64 + p16) ^ s1));
      bf16x8 bl0 = *(const bf16x8*)(smem + LDS_A0L + row0*384 + ((kt*64 + p16) ^ s0));
      bf16x8 bl1 = *(const bf16x8*)(smem + LDS_A0L + row1*384 + ((kt*64 + p16) ^ s1));
      bf16x8 wa[4], wl[4];
      #pragma unroll
      for (int q=0;q<4;++q){
        wa[q] = *(const bf16x8*)(W0p + (((8*q+w)*12 + kt)*64 + lane)*8);
        wl[q] = *(const bf16x8*)(W0p + (((8*q+w)*12 + 6 + kt)*64 + lane)*8);
      }
      #pragma unroll
      for (int q=0;q<4;++q){
        f32x4 c0i = kt ? acc[0][q] : base_r[0][q];
        f32x4 c1i = kt ? acc[1][q] : base_r[1][q];
        acc[0][q] = MFMA16(wa[q], bh0, c0i);
        acc[1][q] = MFMA16(wa[q], bh1, c1i);
      }
      #pragma unroll
      for (int q=0;q<4;++q){
        acc[0][q] = MFMA16(wa[q], bl0, acc[0][q]);
        acc[1][q] = MFMA16(wa[q], bl1, acc[1][q]);
      }
      #pragma unroll
      for (int q=0;q<4;++q){
        acc[0][q] = MFMA16(wl[q], bh0, acc[0][q]);
        acc[1][q] = MFMA16(wl[q], bh1, acc[1][q]);
      }
    }
    lstm_tail(0);
  }

  // ---- persistent step weights Wc (hi+lo) in registers: 32 frags = 128 VGPR ----
  const unsigned short* WCp = wsu + OFF_WC/2;
  bf16x8 wchi[4][4], wclo[4][4];
  #pragma unroll
  for (int q=0;q<4;++q){
    #pragma unroll
    for (int kt=0;kt<4;++kt){
      wchi[q][kt] = *(const bf16x8*)(WCp + (((8*q+w)*8 + kt)*64 + lane)*8);
      wclo[q][kt] = *(const bf16x8*)(WCp + (((8*q+w)*8 + 4 + kt)*64 + lane)*8);
    }
  }
  __syncthreads();

  // ---- t = 1..T-1: gates = base + Wc(A) x h^T(B); term-major MFMA (dep distance 8) ----
  for (int t=1; t<T; ++t){
    *(f32x4*)(outp0 + (t-1)*128) = hcur0;     // store prev step (vmcnt hidden by MFMAs)
    *(f32x4*)(outp1 + (t-1)*128) = hcur1;
    const int rb = (t-1)&1, wb = t&1;
    const char* hb = smem + LDS_H + rb*2*8192;
    #pragma unroll
    for (int kt=0; kt<4; ++kt){
      bf16x8 bh0 = *(const bf16x8*)(hb + row0*256 + ((kt*64 + p16) ^ s0));
      bf16x8 bh1 = *(const bf16x8*)(hb + row1*256 + ((kt*64 + p16) ^ s1));
      bf16x8 bl0 = *(const bf16x8*)(hb + 8192 + row0*256 + ((kt*64 + p16) ^ s0));
      bf16x8 bl1 = *(const bf16x8*)(hb + 8192 + row1*256 + ((kt*64 + p16) ^ s1));
      #pragma unroll
      for (int q=0;q<4;++q){
        f32x4 c0i = kt ? acc[0][q] : base_r[0][q];
        f32x4 c1i = kt ? acc[1][q] : base_r[1][q];
        acc[0][q] = MFMA16(wchi[q][kt], bh0, c0i);
        acc[1][q] = MFMA16(wchi[q][kt], bh1, c1i);
      }
      #pragma unroll
      for (int q=0;q<4;++q){
        acc[0][q] = MFMA16(wchi[q][kt], bl0, acc[0][q]);
        acc[1][q] = MFMA16(wchi[q][kt], bl1, acc[1][q]);
      }
      #pragma unroll
      for (int q=0;q<4;++q){
        acc[0][q] = MFMA16(wclo[q][kt], bh0, acc[0][q]);
        acc[1][q] = MFMA16(wclo[q][kt], bh1, acc[1][q]);
      }
    }
    lstm_tail(wb);
    __syncthreads();
  }
  *(f32x4*)(outp0 + (T-1)*128) = hcur0;
  *(f32x4*)(outp1 + (T-1)*128) = hcur1;
}

extern "C" void kernel_launch(void* const* d_in, const int* in_sizes, int n_in,
                              void* d_out, int out_size, void* d_ws, size_t ws_size,
                              hipStream_t stream) {
    (void)in_sizes; (void)n_in; (void)out_size; (void)ws_size;
    const float* x    = (const float*)d_in[0];
    const float* enc  = (const float*)d_in[1];
    const float* z    = (const float*)d_in[2];
    const float* W_ih = (const float*)d_in[3];
    const float* W_hh = (const float*)d_in[4];
    const float* b_ih = (const float*)d_in[5];
    const float* b_hh = (const float*)d_in[6];
    const float* W_u0 = (const float*)d_in[7];
    const float* b_u0 = (const float*)d_in[8];
    const float* W_h1 = (const float*)d_in[9];
    const float* b_h1 = (const float*)d_in[10];
    const float* W_h2 = (const float*)d_in[11];
    const float* b_h2 = (const float*)d_in[12];
    const int*   hz   = (const int*)d_in[13];
    float* out = (float*)d_out;
    unsigned short* wsu = (unsigned short*)d_ws;
    float* bias = (float*)((char*)d_ws + OFF_BIAS);
    float* wsf  = (float*)d_ws;

    (void)hipFuncSetAttribute((const void*)decoder_main,
                              hipFuncAttributeMaxDynamicSharedMemorySize, LDS_TOTAL);

    decoder_compose<<<dim3(48), dim3(256), 0, stream>>>(W_ih, W_u0, b_u0, W_h1, W_h2, wsf);
    decoder_pack<<<dim3(227), dim3(256), 0, stream>>>(W_ih, W_hh, b_ih, b_hh,
                                                      W_h1, W_h2, b_h1, b_h2, wsu, wsf);
    decoder_main<<<dim3(256), dim3(512), LDS_TOTAL, stream>>>(x, enc, z, wsu, bias, hz, out);
}

// Round 4
// 364.240 us; speedup vs baseline: 1.0433x; 1.0292x over previous
//
#include <hip/hip_runtime.h>
#include <stdint.h>

typedef short bf16x8 __attribute__((ext_vector_type(8)));     // 8 bf16 (4 VGPRs)
typedef float f32x4 __attribute__((ext_vector_type(4)));
typedef unsigned int u32x2 __attribute__((ext_vector_type(2)));

#define MFMA16(a,b,c) __builtin_amdgcn_mfma_f32_16x16x32_bf16((a),(b),(c),0,0,0)

__device__ __forceinline__ unsigned short bf16_rne(float f){
  unsigned int u = __builtin_bit_cast(unsigned int, f);
  return (unsigned short)((u + 0x7FFFu + ((u>>16)&1u)) >> 16);
}
__device__ __forceinline__ float bf16_f(unsigned short h){
  unsigned int u = ((unsigned int)h) << 16;
  return __builtin_bit_cast(float, u);
}

// trunc-split: hi = top16(v) (RTZ), lo = top16(v - hi) (RTZ). Packed pairs for b64 LDS stores.
__device__ __forceinline__ void trunc_split_pack(const f32x4& hv, u32x2& ph, u32x2& pl){
  unsigned b0=__builtin_bit_cast(unsigned,hv[0]);
  unsigned b1=__builtin_bit_cast(unsigned,hv[1]);
  unsigned b2=__builtin_bit_cast(unsigned,hv[2]);
  unsigned b3=__builtin_bit_cast(unsigned,hv[3]);
  ph[0]=(b1&0xFFFF0000u)|(b0>>16);
  ph[1]=(b3&0xFFFF0000u)|(b2>>16);
  float r0=hv[0]-__builtin_bit_cast(float,b0&0xFFFF0000u);
  float r1=hv[1]-__builtin_bit_cast(float,b1&0xFFFF0000u);
  float r2=hv[2]-__builtin_bit_cast(float,b2&0xFFFF0000u);
  float r3=hv[3]-__builtin_bit_cast(float,b3&0xFFFF0000u);
  unsigned c0=__builtin_bit_cast(unsigned,r0);
  unsigned c1=__builtin_bit_cast(unsigned,r1);
  unsigned c2=__builtin_bit_cast(unsigned,r2);
  unsigned c3=__builtin_bit_cast(unsigned,r3);
  pl[0]=(c1&0xFFFF0000u)|(c0>>16);
  pl[1]=(c3&0xFFFF0000u)|(c2>>16);
}

// ---------------- workspace layout (bytes) ----------------
// Packed A-fragment streams: [nt][2*KT slots: hi then lo][lane 0..63][j 0..7] bf16
#define SZ_WINIT (48*24*512*2)            // W_init' [768 x 384], KT=12
#define OFF_W0   (SZ_WINIT)
#define SZ_W0    (32*12*512*2)            // W0'    [512 x 192], KT=6
#define OFF_WC   (OFF_W0 + SZ_W0)
#define SZ_WC    (32*8*512*2)             // Wc     [512 x 128], KT=4
#define OFF_BIAS (OFF_WC + SZ_WC)         // bias_init [768] f32
#define OFF_XQ   (OFF_BIAS + 4096)        // Xq [512 x 49] f32 (W_ih_y @ [W_u0 | b_u0])
#define OFF_XH   (OFF_XQ + 512*49*4)      // Xh [256 x 49] f32 (W_h1/2_y @ [W_u0 | b_u0])

// ---------- P1: compose the u0-foldings (tiny GEMMs, LDS-tiled) ----------
__global__ __launch_bounds__(256)
void decoder_compose(const float* __restrict__ W_ih, const float* __restrict__ W_u0,
                     const float* __restrict__ b_u0, const float* __restrict__ W_h1,
                     const float* __restrict__ W_h2, float* __restrict__ ws){
  __shared__ float wu[128][49];
  __shared__ float wrow[16][128];
  float* Xq = (float*)((char*)ws + OFF_XQ);
  float* Xh = (float*)((char*)ws + OFF_XH);
  const int b = blockIdx.x, tid = threadIdx.x;
  for (int i = tid; i < 128*49; i += 256){
    int c = i/49, j = i - c*49;
    wu[c][j] = (j < 48) ? W_u0[c*48 + j] : b_u0[c];
  }
  for (int i = tid; i < 16*128; i += 256){
    int r = i>>7, c = i&127;
    const float* src;
    if (b < 32) src = W_ih + (b*16 + r)*448 + 64;
    else { int mm = (b-32)*16 + r; src = (mm<128) ? (W_h1 + mm*448 + 64) : (W_h2 + (mm-128)*448 + 64); }
    wrow[r][c] = src[c];
  }
  __syncthreads();
  for (int o = tid; o < 16*49; o += 256){
    int r = o/49, j = o - r*49;
    float s = 0.f;
    #pragma unroll 8
    for (int c = 0; c < 128; ++c) s += wrow[r][c]*wu[c][j];
    if (b < 32) Xq[(b*16+r)*49 + j] = s;
    else        Xh[((b-32)*16+r)*49 + j] = s;
  }
}

// ---------- P2: pack split-bf16 fragment streams (1 thread = 1 fragment) ----------
__global__ __launch_bounds__(256)
void decoder_pack(const float* __restrict__ W_ih, const float* __restrict__ W_hh,
                  const float* __restrict__ b_ih, const float* __restrict__ b_hh,
                  const float* __restrict__ W_h1, const float* __restrict__ W_h2,
                  const float* __restrict__ b_h1, const float* __restrict__ b_h2,
                  unsigned short* __restrict__ wsu, float* __restrict__ ws){
  const float* Xq = (const float*)((const char*)ws + OFF_XQ);
  const float* Xh = (const float*)((const char*)ws + OFF_XH);
  float* bias = (float*)((char*)ws + OFF_BIAS);
  const int gid = blockIdx.x*256 + threadIdx.x;
  const int slot = gid >> 6, lane = gid & 63;
  const int n16 = lane & 15, p = lane >> 4;

  float v[8];
  unsigned short* dh; unsigned short* dl;
  if (slot < 576) {                        // W_init' [768 x 384], KT=12
    int nt = slot/12, kt = slot - nt*12;
    int n = nt*16 + n16;
    #pragma unroll
    for (int j=0;j<8;++j){
      int k = kt*32 + p*8 + j;
      float xv = 0.f;
      if (n < 256) {
        const float* W = (n<128) ? (W_h1 + n*448) : (W_h2 + (n-128)*448);
        if (k < 64) xv = W[k];
        else if (k < 320) xv = W[192 + k - 64];
        else if (k < 368) xv = Xh[n*49 + (k-320)];
      } else {
        int m = n - 256;
        if (k < 64) xv = W_ih[m*448 + k];
        else if (k < 320) xv = W_ih[m*448 + 192 + k - 64];
      }
      v[j] = xv;
    }
    dh = wsu + ((nt*24 + kt)*64 + lane)*8;
    dl = wsu + ((nt*24 + 12 + kt)*64 + lane)*8;
  } else if (slot < 768) {                 // W0' [512 x 192], KT=6
    int s2 = slot - 576;
    int nt = s2/6, kt = s2 - nt*6;
    int n = nt*16 + n16;
    #pragma unroll
    for (int j=0;j<8;++j){
      int k = kt*32 + p*8 + j;
      float xv = 0.f;
      if (k < 49)      xv = Xq[n*49 + k];
      else if (k >= 64) xv = W_hh[n*128 + k - 64];
      v[j] = xv;
    }
    unsigned short* b = wsu + OFF_W0/2;
    dh = b + ((nt*12 + kt)*64 + lane)*8;
    dl = b + ((nt*12 + 6 + kt)*64 + lane)*8;
  } else if (slot < 896) {                 // Wc [512 x 128], KT=4
    int s3 = slot - 768;
    int nt = s3>>2, kt = s3&3;
    int n = nt*16 + n16;
    #pragma unroll
    for (int j=0;j<8;++j){
      int k = kt*32 + p*8 + j;
      v[j] = W_ih[n*448 + 64 + k] + W_hh[n*128 + k];
    }
    unsigned short* b = wsu + OFF_WC/2;
    dh = b + ((nt*8 + kt)*64 + lane)*8;
    dl = b + ((nt*8 + 4 + kt)*64 + lane)*8;
  } else {                                 // bias_init [768]
    int i = gid - 896*64;
    if (i < 768) {
      float bv;
      if (i < 128)      bv = b_h1[i] + Xh[i*49 + 48];
      else if (i < 256) bv = b_h2[i-128] + Xh[i*49 + 48];
      else              bv = b_ih[i-256] + b_hh[i-256];
      bias[i] = bv;
    }
    return;
  }
  bf16x8 vh, vl;
  #pragma unroll
  for (int j=0;j<8;++j){
    unsigned short h = bf16_rne(v[j]);
    vh[j] = (short)h;
    vl[j] = (short)bf16_rne(v[j] - bf16_f(h));
  }
  *(bf16x8*)dh = vh;
  *(bf16x8*)dl = vl;
}

// ---------------- LDS layout (bytes) ----------------
// Pitches chosen so pitch/4 mod 32 == 4 -> row r and r+8 alias (2-way = free), b128 reads
// hit the 8-cycle floor with zero extra conflict.
// [0     ,12800) a0_hi [32 rows][192 K] bf16, pitch 400B
// [12800 ,25600) a0_lo
// [25600 ,50688) xi_hi [32][384], pitch 784B              -- dead after setup
// [50688 ,75776) xi_lo
// overlay after setup (single-buffered per batch-tile, write/read alternate phases):
// [25600 ,43008) h[g][plane]: 4 x [16][pitch 272B]
#define P_H   272
#define P_A0  400
#define P_XI  784
#define LDS_A0H 0
#define LDS_A0L 12800
#define LDS_XIH 25600
#define LDS_XIL 50688
#define LDS_HB  25600
#define LDS_ALLOC 81920   // > 80KB: pins 1 block/CU (avoid 2-block imbalance)

__global__ __launch_bounds__(512) __attribute__((amdgpu_waves_per_eu(2, 2)))
void decoder_main(const float* __restrict__ x, const float* __restrict__ enc,
                  const float* __restrict__ z, const unsigned short* __restrict__ wsu,
                  const float* __restrict__ bias, const int* __restrict__ hz,
                  float* __restrict__ out){
  extern __shared__ char smem[];
  const int tid = threadIdx.x;
  const int w = tid>>6, lane = tid&63, n16 = lane&15, p = lane>>4;
  const int p16 = p*16;
  const int R0 = blockIdx.x*32;
  const int T = hz[0];

  // ---- stage split inputs ----
  for (int i = tid; i < 32*384; i += 512){
    int r = i/384, c = i - r*384;
    float v;
    if (c < 64)       v = z[(R0+r)*64 + c];
    else if (c < 320) v = enc[(R0+r)*256 + c - 64];
    else if (c < 368) v = x[(R0+r)*48 + c - 320];
    else              v = 0.f;
    unsigned short h = bf16_rne(v);
    *(unsigned short*)(smem + LDS_XIH + r*P_XI + 2*c) = h;
    *(unsigned short*)(smem + LDS_XIL + r*P_XI + 2*c) = bf16_rne(v - bf16_f(h));
  }
  for (int i = tid; i < 32*64; i += 512){
    int r = i>>6, c = i&63;
    float v = (c < 48) ? x[(R0+r)*48 + c] : (c == 48 ? 1.f : 0.f);
    unsigned short h = bf16_rne(v);
    *(unsigned short*)(smem + LDS_A0H + r*P_A0 + 2*c) = h;
    *(unsigned short*)(smem + LDS_A0L + r*P_A0 + 2*c) = bf16_rne(v - bf16_f(h));
  }
  __syncthreads();

  // ---- setup GEMM: D[768 units][32 batch] = W_init'(A) x xi^T(B) + bias ----
  // wave w tiles: i=0 -> w (h0init), i=1 -> 8+w (c0init), i=2+q -> 16+8q+w (base gate q)
  f32x4 accs[6][2];
  #pragma unroll
  for (int i=0;i<6;++i){
    int nt = (i==0) ? w : (i==1) ? (8+w) : (16 + 8*(i-2) + w);
    f32x4 bv = *(const f32x4*)(bias + nt*16 + p*4);
    accs[i][0] = bv; accs[i][1] = bv;
  }
  #pragma unroll
  for (int kt=0; kt<12; ++kt){
    bf16x8 bh0 = *(const bf16x8*)(smem + LDS_XIH + n16*P_XI      + kt*64 + p16);
    bf16x8 bh1 = *(const bf16x8*)(smem + LDS_XIH + (16+n16)*P_XI + kt*64 + p16);
    bf16x8 bl0 = *(const bf16x8*)(smem + LDS_XIL + n16*P_XI      + kt*64 + p16);
    bf16x8 bl1 = *(const bf16x8*)(smem + LDS_XIL + (16+n16)*P_XI + kt*64 + p16);
    bf16x8 wa[6], wl[6];
    #pragma unroll
    for (int i=0;i<6;++i){
      if (kt >= 10 && i >= 2) continue;      // base x-columns are zero
      int nt = (i==0) ? w : (i==1) ? (8+w) : (16 + 8*(i-2) + w);
      wa[i] = *(const bf16x8*)(wsu + ((nt*24 + kt)*64 + lane)*8);
      wl[i] = *(const bf16x8*)(wsu + ((nt*24 + 12 + kt)*64 + lane)*8);
    }
    #pragma unroll
    for (int i=0;i<6;++i){ if (kt >= 10 && i >= 2) continue;
      accs[i][0] = MFMA16(wa[i], bh0, accs[i][0]);
      accs[i][1] = MFMA16(wa[i], bh1, accs[i][1]); }
    #pragma unroll
    for (int i=0;i<6;++i){ if (kt >= 10 && i >= 2) continue;
      accs[i][0] = MFMA16(wa[i], bl0, accs[i][0]);
      accs[i][1] = MFMA16(wa[i], bl1, accs[i][1]); }
    #pragma unroll
    for (int i=0;i<6;++i){ if (kt >= 10 && i >= 2) continue;
      accs[i][0] = MFMA16(wl[i], bh0, accs[i][0]);
      accs[i][1] = MFMA16(wl[i], bh1, accs[i][1]); }
  }

  // ---- publish h0init into a0 cols 64+u; c0/base stay in regs ----
  #pragma unroll
  for (int g=0; g<2; ++g){
    u32x2 ph, pl;
    trunc_split_pack(accs[0][g], ph, pl);
    int off = (g*16 + n16)*P_A0 + 128 + 32*w + 8*p;
    *(u32x2*)(smem + LDS_A0H + off) = ph;
    *(u32x2*)(smem + LDS_A0L + off) = pl;
  }
  f32x4 creg0 = accs[1][0], creg1 = accs[1][1];
  f32x4 base0[4], base1[4];
  #pragma unroll
  for (int q=0;q<4;++q){ base0[q] = accs[2+q][0]; base1[q] = accs[2+q][1]; }
  __syncthreads();   // a0 complete; xi dead -> h buffers may be written after this

  char* h0H = smem + LDS_HB;
  char* h0L = smem + LDS_HB + 4352;
  char* h1H = smem + LDS_HB + 8704;
  char* h1L = smem + LDS_HB + 13056;

  f32x4 acc0[4], acc1[4];
  f32x4 hcur0, hcur1;
  const float K1 = 1.44269504088896340736f;   // log2(e)
  const float K2 = 2.88539008177792681472f;   // 2*log2(e)

  // LSTM cell tail: thread owns gates i/f/g/o (q) for units 16w+4p+e, one batch row (n16 of tile)
  auto tailg = [&](const f32x4 (&ag)[4], f32x4 &cr, f32x4 &hc,
                   char* hbH, char* hbL, bool wr){
    f32x4 hv;
    #pragma unroll
    for (int e=0;e<4;++e){
      float iv = ag[0][e], fv = ag[1][e], gv = ag[2][e], ov = ag[3][e];
      float c = cr[e];
      float ef = __builtin_amdgcn_exp2f(-K1*fv);
      float sf = __builtin_amdgcn_rcpf(1.f + ef);                    // sigmoid(f)
      float ei = __builtin_amdgcn_exp2f(-K1*iv);
      float eg = __builtin_amdgcn_exp2f(-K2*gv);
      float d  = __builtin_amdgcn_rcpf((1.f+ei)*(1.f+eg));
      c = sf*c + (1.f-eg)*d;                                         // + sig(i)*tanh(g)
      float eo = __builtin_amdgcn_exp2f(-K1*ov);
      float ec = __builtin_amdgcn_exp2f(-K2*c);
      float h  = (1.f-ec)*__builtin_amdgcn_rcpf((1.f+eo)*(1.f+ec));  // sig(o)*tanh(c)
      cr[e] = c; hv[e] = h;
    }
    hc = hv;
    u32x2 ph, pl;
    trunc_split_pack(hv, ph, pl);
    if (wr){
      int off = n16*P_H + 32*w + 8*p;
      *(u32x2*)(hbH + off) = ph;
      *(u32x2*)(hbL + off) = pl;
    }
  };

  // ---- t = 0: gates = base + W0'(A) x [x|1|h0init]^T(B), both batch tiles ----
  {
    const unsigned short* W0p = wsu + OFF_W0/2;
    #pragma unroll
    for (int kt=0; kt<6; ++kt){
      bf16x8 bh0 = *(const bf16x8*)(smem + LDS_A0H + n16*P_A0      + kt*64 + p16);
      bf16x8 bh1 = *(const bf16x8*)(smem + LDS_A0H + (16+n16)*P_A0 + kt*64 + p16);
      bf16x8 bl0 = *(const bf16x8*)(smem + LDS_A0L + n16*P_A0      + kt*64 + p16);
      bf16x8 bl1 = *(const bf16x8*)(smem + LDS_A0L + (16+n16)*P_A0 + kt*64 + p16);
      bf16x8 wh[4], wl[4];
      #pragma unroll
      for (int q=0;q<4;++q){
        wh[q] = *(const bf16x8*)(W0p + (((8*q+w)*12 + kt)*64 + lane)*8);
        wl[q] = *(const bf16x8*)(W0p + (((8*q+w)*12 + 6 + kt)*64 + lane)*8);
      }
      #pragma unroll
      for (int q=0;q<4;++q){
        acc0[q] = MFMA16(wh[q], bh0, kt ? acc0[q] : base0[q]);
        acc1[q] = MFMA16(wh[q], bh1, kt ? acc1[q] : base1[q]);
      }
      #pragma unroll
      for (int q=0;q<4;++q){
        acc0[q] = MFMA16(wh[q], bl0, acc0[q]);
        acc1[q] = MFMA16(wh[q], bl1, acc1[q]);
      }
      #pragma unroll
      for (int q=0;q<4;++q){
        acc0[q] = MFMA16(wl[q], bh0, acc0[q]);
        acc1[q] = MFMA16(wl[q], bh1, acc1[q]);
      }
    }
  }
  tailg(acc0, creg0, hcur0, h0H, h0L, true);     // L0(0): h0[0] -> LDS, hcur0

  // ---- resident step weights Wc (hi+lo): 32 frags = 128 VGPR, loaded once ----
  const unsigned short* WCp = wsu + OFF_WC/2;
  bf16x8 wchi[4][4], wclo[4][4];
  #pragma unroll
  for (int q=0;q<4;++q){
    #pragma unroll
    for (int kt=0;kt<4;++kt){
      wchi[q][kt] = *(const bf16x8*)(WCp + (((8*q+w)*8 + kt)*64 + lane)*8);
      wclo[q][kt] = *(const bf16x8*)(WCp + (((8*q+w)*8 + 4 + kt)*64 + lane)*8);
    }
  }
  __syncthreads();

  // step-gates MFMA for one batch tile: acc = base + Wc x h^T (3 split terms)
  auto gphase = [&](f32x4 (&ag)[4], const f32x4 (&bs)[4], const char* hH, const char* hL){
    #pragma unroll
    for (int kt=0; kt<4; ++kt){
      bf16x8 bh = *(const bf16x8*)(hH + n16*P_H + kt*64 + p16);
      bf16x8 bl = *(const bf16x8*)(hL + n16*P_H + kt*64 + p16);
      if (kt == 0){
        #pragma unroll
        for (int q=0;q<4;++q) ag[q] = MFMA16(wchi[q][0], bh, bs[q]);
      } else {
        #pragma unroll
        for (int q=0;q<4;++q) ag[q] = MFMA16(wchi[q][kt], bh, ag[q]);
      }
      #pragma unroll
      for (int q=0;q<4;++q) ag[q] = MFMA16(wchi[q][kt], bl, ag[q]);
      #pragma unroll
      for (int q=0;q<4;++q) ag[q] = MFMA16(wclo[q][kt], bh, ag[q]);
    }
  };

  float* op0 = out + (size_t)(R0 + n16)      * (size_t)(T*128) + (16*w + 4*p);
  float* op1 = out + (size_t)(R0 + 16 + n16) * (size_t)(T*128) + (16*w + 4*p);

  // ---- steady: half-step pipeline, 2 barriers/step ----
  // phase(0,t): store h0[t-1] | MFMA gates(bt0,t) | tail(bt1,t-1) -> h1 LDS
  // phase(1,t): store h1[t-1] | MFMA gates(bt1,t) | tail(bt0,t)   -> h0 LDS
  for (int t=1; t<T; ++t){
    *(f32x4*)op0 = hcur0; op0 += 128;
    gphase(acc0, base0, h0H, h0L);
    tailg(acc1, creg1, hcur1, h1H, h1L, true);
    __syncthreads();

    *(f32x4*)op1 = hcur1; op1 += 128;
    gphase(acc1, base1, h1H, h1L);
    tailg(acc0, creg0, hcur0, h0H, h0L, true);
    __syncthreads();
  }
  // epilogue: pending h0[T-1]; finish bt1's last tail; store both
  *(f32x4*)op0 = hcur0;
  tailg(acc1, creg1, hcur1, h1H, h1L, false);
  *(f32x4*)op1 = hcur1;
}

extern "C" void kernel_launch(void* const* d_in, const int* in_sizes, int n_in,
                              void* d_out, int out_size, void* d_ws, size_t ws_size,
                              hipStream_t stream) {
    (void)in_sizes; (void)n_in; (void)out_size; (void)ws_size;
    const float* x    = (const float*)d_in[0];
    const float* enc  = (const float*)d_in[1];
    const float* z    = (const float*)d_in[2];
    const float* W_ih = (const float*)d_in[3];
    const float* W_hh = (const float*)d_in[4];
    const float* b_ih = (const float*)d_in[5];
    const float* b_hh = (const float*)d_in[6];
    const float* W_u0 = (const float*)d_in[7];
    const float* b_u0 = (const float*)d_in[8];
    const float* W_h1 = (const float*)d_in[9];
    const float* b_h1 = (const float*)d_in[10];
    const float* W_h2 = (const float*)d_in[11];
    const float* b_h2 = (const float*)d_in[12];
    const int*   hz   = (const int*)d_in[13];
    float* out = (float*)d_out;
    unsigned short* wsu = (unsigned short*)d_ws;
    float* bias = (float*)((char*)d_ws + OFF_BIAS);
    float* wsf  = (float*)d_ws;

    (void)hipFuncSetAttribute((const void*)decoder_main,
                              hipFuncAttributeMaxDynamicSharedMemorySize, LDS_ALLOC);

    decoder_compose<<<dim3(48), dim3(256), 0, stream>>>(W_ih, W_u0, b_u0, W_h1, W_h2, wsf);
    decoder_pack<<<dim3(227), dim3(256), 0, stream>>>(W_ih, W_hh, b_ih, b_hh,
                                                      W_h1, W_h2, b_h1, b_h2, wsu, wsf);
    decoder_main<<<dim3(256), dim3(512), LDS_ALLOC, stream>>>(x, enc, z, wsu, bias, hz, out);
}